// Round 9
// baseline (5490.268 us; speedup 1.0000x reference)
//
#include <hip/hip_runtime.h>

#define ZB 202
#define ZBP 208            // imgT row stride (floats): [0,1,2]=zeros(bands -3..-1), 3+z=band z
#define YX 65536
#define NTOT ((size_t)ZB * YX)

#define SS 128             // steps per superstep (LDS: 2 x 128 x 256B = 64 KB)
#define NSS (YX / SS)      // 512 supersteps
#define PAD 4              // front slack so lanes 0-2's (lane-3) reads stay in-bounds

__device__ __forceinline__ constexpr float kMU() { return 0.0009765625f; }  // 2^-10
#define MINV (-32768.0f)
#define MAXV (32767.0f)

typedef float v2f __attribute__((ext_vector_type(2)));

// global->LDS direct DMA, dword: per-lane global addr, LDS dest = uniform base + lane*4
#define GL_LDS4(g, l)                                                     \
    __builtin_amdgcn_global_load_lds(                                     \
        (const __attribute__((address_space(1))) void*)(g),               \
        (__attribute__((address_space(3))) void*)(l), 4, 0, 0)

// ---------------------------------------------------------------------------
// Phase A: transpose img[z][t] -> imgT[t*ZBP + 3 + z], zeros at offsets 0-2 and
// 205-207. (unchanged, verified round 3)
// ---------------------------------------------------------------------------
__global__ __launch_bounds__(256) void tr_kernel(const float* __restrict__ img,
                                                 float* __restrict__ imgT) {
    __shared__ float lds[64 * 65];
    const int t0 = blockIdx.x * 64;
    const int zi = blockIdx.y;           // 0..3
    const int zw0 = zi * 64 - 3;         // window band base
    const int tid = threadIdx.x;
    const int c = tid & 63;
    const int r0 = tid >> 6;

    for (int k = 0; k < 16; ++k) {
        int rr = r0 * 16 + k;
        int z = zw0 + rr;
        float v = 0.0f;
        if (z >= 0 && z < ZB) v = img[(size_t)z * YX + t0 + c];  // coalesced along t
        lds[rr * 65 + c] = v;
    }
    __syncthreads();

    const int l = tid & 63;
    const int off = zi * 64 + l;
    if (off < ZBP) {
        for (int k = 0; k < 16; ++k) {
            int tr = r0 * 16 + k;
            imgT[(size_t)(t0 + tr) * ZBP + off] = lds[l * 65 + tr];  // coalesced along z
        }
    }
}

// ---------------------------------------------------------------------------
// Phase B: sequential sign-LMS scan — producer/consumer (round-6 shell) with a
// CANDIDATE-SELECT consumer.
//
// Round-8 post-mortem: (a) asm-output->array copies raced the async LDS return
// (movs scheduled before lgkmcnt(0)); fixed here by making the asm write the
// long-lived arrays DIRECTLY ("=&v"(Aa[k])) so no register is read before the
// wait.  (b) more chains/SIMD can't shorten wall-clock: 65536 steps x per-wave
// chain is the floor.  So round 9 shortens the CHAIN: since sg in {+MU,-MU,0},
// precompute off-chain the three candidate weight sets (fma(+-MU,n,w)) and the
// three candidate d(t+1) values (identical op order as the original dot), then
// the serial chain per step is only cmp -> cndmask -> cndmask (~3.5 deps vs 7).
// Bit-exact: every selected candidate is the exact instruction sequence the
// original recurrence would have executed (fma(+-MU,n,w) == fma(sg,n,w);
// candidate dots == the original 3-mul + left-to-right 2-add with the selected
// w).  sign(s-clip(d)) == sign(s-d) since |s| < 32767.  Stores UNCLIPPED d.
//
// Sub-tile pipeline: 16-step sub-tiles, A/B ping-pong, reads issued one
// sub-tile ahead, drained by KWAIT (lgkmcnt(0)+sched_barrier, rule #18).
// Steps 0..13 prep candidates from buf[i+1], buf[i+2]; step 14 preps w-cands
// only (buf[15]); step 15 does cmp+w-select only; BOUNDARY (after KWAIT)
// recomputes dc = dot(w, n_next0) directly (bit-exact ≡ the skipped select)
// and preps candidates from next[0], next[1].
// ---------------------------------------------------------------------------
__global__ __launch_bounds__(512, 1) void scan_kernel(const float* __restrict__ imgT,
                                                      const float* __restrict__ w0g,
                                                      float* __restrict__ dT) {
    __shared__ float ldsf[PAD + 2 * SS * 64];  // 64.02 KB

    const int tid = threadIdx.x;
    const int lane = tid & 63;
    const int wv = tid >> 6;                  // 0 = consumer, 1..7 = producers
    const int b = blockIdx.x;                 // 0..3
    const int goff = 61 * b + lane;           // imgT row offset this lane loads
    const float* gsrc = imgT + goff;

    // consumer-only state (harmless on producers)
    const int band = 61 * b + lane - 3;
    const bool do_store = (lane >= 3) && (band < ZB);
    const int wband = band < 0 ? 0 : (band > ZB - 1 ? ZB - 1 : band);
    float w0 = w0g[wband * 3 + 0];
    float w1 = w0g[wband * 3 + 1];
    float w2 = w0g[wband * 3 + 2];
    float* outp = dT + wband;                 // dT[t][z] layout, stride ZB

    // producer: stage superstep st into buffer st&1 (rows strided by 7 waves)
    auto stage = [&](int st) {
        float* lp = ldsf + PAD + (st & 1) * (SS * 64);
        const float* gp = gsrc + (size_t)st * (SS * ZBP);
        for (int r = wv - 1; r < SS; r += 7)
            GL_LDS4(gp + (size_t)r * ZBP, lp + r * 64);
    };

    // sub-tile register buffers: Xa[k] = {nx(lane-3), ny(lane-2)},
    //                            Xb[k] = {nz(lane-1), s(lane)}
    v2f Aa[16], Ab[16], Ba[16], Bb[16];

    // running candidate state
    float dc;                                  // d(t) for the current step
    float c_w0p, c_w0m, c_w1p, c_w1m, c_w2p, c_w2m;  // w(t) candidates
    float c_dP, c_dM, c_d0;                    // d(t+1) candidates
    float* op = nullptr;

    // batch-ISSUE one 16-step sub-tile; asm writes the ARRAYS directly (no
    // intermediate copies -> nothing can read the regs before KWAIT).
#define RTISSUE(XA, XB, bsel, st_)                                             \
    {                                                                          \
        uint32_t a0_ = (uint32_t)(size_t)(__attribute__((address_space(3)))    \
            float*)(ldsf + (PAD + (bsel) * (SS * 64) + (st_) * (16 * 64)       \
                            + lane - 3));                                      \
        _Pragma("unroll") for (int k = 0; k < 16; ++k) {                       \
            uint32_t a_ = a0_ + (uint32_t)(k * 256);                           \
            asm volatile("ds_read2_b32 %0, %2 offset0:0 offset1:1\n\t"         \
                         "ds_read2_b32 %1, %2 offset0:2 offset1:3"             \
                         : "=&v"(XA[k]), "=&v"(XB[k])                          \
                         : "v"(a_));                                           \
        }                                                                      \
    }

#define KWAIT()                                                                \
    {                                                                          \
        asm volatile("s_waitcnt lgkmcnt(0)" ::: "memory");                     \
        __builtin_amdgcn_sched_barrier(0);                                     \
    }

    // one full step: store d(t); select w(t), d(t+1); prep candidates for t+1
#define STEP_FULL(BA, BB, i_)                                                  \
    {                                                                          \
        const float s_ = BB[i_].y;                                             \
        if (do_store) op[(size_t)(i_) * ZB] = dc;                              \
        const bool cp_ = s_ > dc, cm_ = s_ < dc;                               \
        const float w0n = cp_ ? c_w0p : (cm_ ? c_w0m : w0);                    \
        const float w1n = cp_ ? c_w1p : (cm_ ? c_w1m : w1);                    \
        const float w2n = cp_ ? c_w2p : (cm_ ? c_w2m : w2);                    \
        const float dn = cp_ ? c_dP : (cm_ ? c_dM : c_d0);                     \
        const float nz1 = BB[(i_) + 1].x, ny1 = BA[(i_) + 1].y,                \
                    nx1 = BA[(i_) + 1].x;                                      \
        c_w0p = __builtin_fmaf(kMU(), nz1, w0n);                               \
        c_w0m = __builtin_fmaf(-kMU(), nz1, w0n);                              \
        c_w1p = __builtin_fmaf(kMU(), ny1, w1n);                               \
        c_w1m = __builtin_fmaf(-kMU(), ny1, w1n);                              \
        c_w2p = __builtin_fmaf(kMU(), nx1, w2n);                               \
        c_w2m = __builtin_fmaf(-kMU(), nx1, w2n);                              \
        const float nz2 = BB[(i_) + 2].x, ny2 = BA[(i_) + 2].y,                \
                    nx2 = BA[(i_) + 2].x;                                      \
        c_dP = __fadd_rn(__fadd_rn(__fmul_rn(c_w0p, nz2), __fmul_rn(c_w1p, ny2)), \
                         __fmul_rn(c_w2p, nx2));                               \
        c_dM = __fadd_rn(__fadd_rn(__fmul_rn(c_w0m, nz2), __fmul_rn(c_w1m, ny2)), \
                         __fmul_rn(c_w2m, nx2));                               \
        c_d0 = __fadd_rn(__fadd_rn(__fmul_rn(w0n, nz2), __fmul_rn(w1n, ny2)),  \
                         __fmul_rn(w2n, nx2));                                 \
        w0 = w0n; w1 = w1n; w2 = w2n; dc = dn;                                 \
    }

    // step 14: d-cand prep needs buf[16] -> skip it (step 15 skips d-select)
#define STEP14(BA, BB)                                                         \
    {                                                                          \
        const float s_ = BB[14].y;                                             \
        if (do_store) op[(size_t)14 * ZB] = dc;                                \
        const bool cp_ = s_ > dc, cm_ = s_ < dc;                               \
        const float w0n = cp_ ? c_w0p : (cm_ ? c_w0m : w0);                    \
        const float w1n = cp_ ? c_w1p : (cm_ ? c_w1m : w1);                    \
        const float w2n = cp_ ? c_w2p : (cm_ ? c_w2m : w2);                    \
        const float dn = cp_ ? c_dP : (cm_ ? c_dM : c_d0);                     \
        const float nz1 = BB[15].x, ny1 = BA[15].y, nx1 = BA[15].x;            \
        c_w0p = __builtin_fmaf(kMU(), nz1, w0n);                               \
        c_w0m = __builtin_fmaf(-kMU(), nz1, w0n);                              \
        c_w1p = __builtin_fmaf(kMU(), ny1, w1n);                               \
        c_w1m = __builtin_fmaf(-kMU(), ny1, w1n);                              \
        c_w2p = __builtin_fmaf(kMU(), nx1, w2n);                               \
        c_w2m = __builtin_fmaf(-kMU(), nx1, w2n);                              \
        w0 = w0n; w1 = w1n; w2 = w2n; dc = dn;                                 \
    }

    // step 15: store + cmp + w-select only; dc refreshed by BOUNDARY
#define STEP15(BA, BB)                                                         \
    {                                                                          \
        const float s_ = BB[15].y;                                             \
        if (do_store) op[(size_t)15 * ZB] = dc;                                \
        const bool cp_ = s_ > dc, cm_ = s_ < dc;                               \
        w0 = cp_ ? c_w0p : (cm_ ? c_w0m : w0);                                 \
        w1 = cp_ ? c_w1p : (cm_ ? c_w1m : w1);                                 \
        w2 = cp_ ? c_w2p : (cm_ ? c_w2m : w2);                                 \
    }

#define CPMAIN(BA, BB)                                                         \
    {                                                                          \
        _Pragma("unroll") for (int i = 0; i < 14; ++i) STEP_FULL(BA, BB, i);   \
        STEP14(BA, BB);                                                        \
        STEP15(BA, BB);                                                        \
    }

    // finish the deferred d (bit-exact: dot with the SELECTED w == the skipped
    // candidate select) and prep candidates from the next sub-tile's [0],[1]
#define BOUNDARY(A0, B0, A1, B1)                                               \
    {                                                                          \
        const float nzb0 = (B0).x, nyb0 = (A0).y, nxb0 = (A0).x;               \
        dc = __fadd_rn(__fadd_rn(__fmul_rn(w0, nzb0), __fmul_rn(w1, nyb0)),    \
                       __fmul_rn(w2, nxb0));                                   \
        c_w0p = __builtin_fmaf(kMU(), nzb0, w0);                               \
        c_w0m = __builtin_fmaf(-kMU(), nzb0, w0);                              \
        c_w1p = __builtin_fmaf(kMU(), nyb0, w1);                               \
        c_w1m = __builtin_fmaf(-kMU(), nyb0, w1);                              \
        c_w2p = __builtin_fmaf(kMU(), nxb0, w2);                               \
        c_w2m = __builtin_fmaf(-kMU(), nxb0, w2);                              \
        const float nzb1 = (B1).x, nyb1 = (A1).y, nxb1 = (A1).x;               \
        c_dP = __fadd_rn(__fadd_rn(__fmul_rn(c_w0p, nzb1), __fmul_rn(c_w1p, nyb1)), \
                         __fmul_rn(c_w2p, nxb1));                              \
        c_dM = __fadd_rn(__fadd_rn(__fmul_rn(c_w0m, nzb1), __fmul_rn(c_w1m, nyb1)), \
                         __fmul_rn(c_w2m, nxb1));                              \
        c_d0 = __fadd_rn(__fadd_rn(__fmul_rn(w0, nzb1), __fmul_rn(w1, nyb1)),  \
                         __fmul_rn(w2, nxb1));                                 \
    }

#define SUBT(CA, CB, NA, NB, stn)                                              \
    op = outp + ((size_t)ss * SS + (stn) * 16) * ZB;                           \
    RTISSUE(NA, NB, csel, (stn) + 1);                                          \
    CPMAIN(CA, CB);                                                            \
    KWAIT();                                                                   \
    BOUNDARY(NA[0], NB[0], NA[1], NB[1]);

    if (wv != 0) stage(0);
    __syncthreads();
    if (wv == 0) {
        // prologue == BOUNDARY with w(-1)=w_init: dc=d(0), cands for step 0
        RTISSUE(Aa, Ab, 0, 0);
        KWAIT();
        BOUNDARY(Aa[0], Ab[0], Aa[1], Ab[1]);
    }

    for (int ss = 0; ss < NSS; ++ss) {
        if (wv != 0) {
            if (ss + 1 < NSS) stage(ss + 1);
        } else {
            const int csel = ss & 1;
            SUBT(Aa, Ab, Ba, Bb, 0)
            SUBT(Ba, Bb, Aa, Ab, 1)
            SUBT(Aa, Ab, Ba, Bb, 2)
            SUBT(Ba, Bb, Aa, Ab, 3)
            SUBT(Aa, Ab, Ba, Bb, 4)
            SUBT(Ba, Bb, Aa, Ab, 5)
            SUBT(Aa, Ab, Ba, Bb, 6)
            op = outp + ((size_t)ss * SS + 7 * 16) * ZB;
            CPMAIN(Ba, Bb);
        }
        __syncthreads();  // producers drained; buffer handoff
        if (wv == 0) {
            if (ss + 1 < NSS) { RTISSUE(Aa, Ab, (ss + 1) & 1, 0); }
            KWAIT();
            BOUNDARY(Aa[0], Ab[0], Aa[1], Ab[1]);  // junk-but-unused on last ss
        }
    }

#undef RTISSUE
#undef KWAIT
#undef STEP_FULL
#undef STEP14
#undef STEP15
#undef CPMAIN
#undef BOUNDARY
#undef SUBT
}

// ---------------------------------------------------------------------------
// Phase C: elementwise outputs from dT + image. (unchanged, verified)
// ---------------------------------------------------------------------------
__global__ __launch_bounds__(256) void finalize_kernel(const float* __restrict__ img,
                                                       const float* __restrict__ dT,
                                                       float* __restrict__ out) {
    __shared__ float lds[64 * ZB];  // 51.7 KB
    const int t0 = blockIdx.x * 64;
    const float* src = dT + (size_t)t0 * ZB;
    for (int i = threadIdx.x; i < 64 * ZB; i += 256) lds[i] = src[i];
    __syncthreads();

    for (int k = 0; k < 51; ++k) {
        int e = k * 256 + threadIdx.x;
        if (e < 64 * ZB) {
            int zz = e >> 6;
            int tl = e & 63;
            float dv = lds[tl * ZB + zz];            // stride 202 -> 2-way bank alias (free)
            float pred = fminf(fmaxf(dv, MINV), MAXV);
            size_t o = (size_t)zz * YX + t0 + tl;
            float s = img[o];
            float res = __fsub_rn(s, pred);
            int q = (int)rintf(res);                  // round-half-even == jnp.round
            int m = (q >= 0) ? (2 * q) : (-2 * q - 1);
            out[o] = pred;                            // predictions
            out[NTOT + o] = res;                      // residuals
            out[2 * NTOT + o] = res;                  // quantized_residuals
            out[3 * NTOT + o] = (float)m;             // mapped_indices
            out[5 * NTOT + o] = __fadd_rn(pred, res); // reconstructed
        }
    }
}

// ---------------------------------------------------------------------------
// Phase D: sample_representatives = image. (unchanged)
// ---------------------------------------------------------------------------
__global__ __launch_bounds__(256) void repr_kernel(const float4* __restrict__ img4,
                                                   float4* __restrict__ out4) {
    size_t n4 = NTOT / 4;
    for (size_t i = (size_t)blockIdx.x * blockDim.x + threadIdx.x; i < n4;
         i += (size_t)gridDim.x * blockDim.x)
        out4[i] = img4[i];
}

extern "C" void kernel_launch(void* const* d_in, const int* in_sizes, int n_in,
                              void* d_out, int out_size, void* d_ws, size_t ws_size,
                              hipStream_t stream) {
    const float* img = (const float*)d_in[0];
    const float* w0g = (const float*)d_in[1];
    float* out = (float*)d_out;

    // Scratch carved out of d_out (dead before the final writers touch it):
    //   imgT = out[0 .. YX*ZBP+64) floats (54.5 MB; +64 slack keeps block-3
    //          tail-lane junk reads in-bounds)
    //   dT   = out[4N .. 5N) floats (later overwritten by repr_kernel)
    float* imgT = out;
    float* dT = out + 4 * NTOT;

    tr_kernel<<<dim3(YX / 64, 4), 256, 0, stream>>>(img, imgT);
    scan_kernel<<<4, 512, 0, stream>>>(imgT, w0g, dT);
    finalize_kernel<<<YX / 64, 256, 0, stream>>>(img, dT, out);
    repr_kernel<<<4096, 256, 0, stream>>>((const float4*)img, (float4*)(out + 4 * NTOT));
}

// Round 10
// 2772.624 us; speedup vs baseline: 1.9802x; 1.9802x over previous
//
#include <hip/hip_runtime.h>

#define ZB 202
#define ZBP 208            // imgT row stride (floats): [0,1,2]=zeros(bands -3..-1), 3+z=band z
#define YX 65536
#define NTOT ((size_t)ZB * YX)

#define SS 128             // steps per superstep (LDS: 2 x 128 x 256B = 64 KB)
#define NSS (YX / SS)      // 512 supersteps
#define PAD 4              // front slack so lanes 0-2's (lane-3) reads stay in-bounds

__device__ __forceinline__ constexpr float kMU() { return 0.0009765625f; }  // 2^-10
#define MINV (-32768.0f)
#define MAXV (32767.0f)

typedef float v2f __attribute__((ext_vector_type(2)));

// global->LDS direct DMA, dword: per-lane global addr, LDS dest = uniform base + lane*4
#define GL_LDS4(g, l)                                                     \
    __builtin_amdgcn_global_load_lds(                                     \
        (const __attribute__((address_space(1))) void*)(g),               \
        (__attribute__((address_space(3))) void*)(l), 4, 0, 0)

// ---------------------------------------------------------------------------
// Phase A: transpose img[z][t] -> imgT[t*ZBP + 3 + z], zeros at offsets 0-2 and
// 205-207. (unchanged, verified round 3)
// ---------------------------------------------------------------------------
__global__ __launch_bounds__(256) void tr_kernel(const float* __restrict__ img,
                                                 float* __restrict__ imgT) {
    __shared__ float lds[64 * 65];
    const int t0 = blockIdx.x * 64;
    const int zi = blockIdx.y;           // 0..3
    const int zw0 = zi * 64 - 3;         // window band base
    const int tid = threadIdx.x;
    const int c = tid & 63;
    const int r0 = tid >> 6;

    for (int k = 0; k < 16; ++k) {
        int rr = r0 * 16 + k;
        int z = zw0 + rr;
        float v = 0.0f;
        if (z >= 0 && z < ZB) v = img[(size_t)z * YX + t0 + c];  // coalesced along t
        lds[rr * 65 + c] = v;
    }
    __syncthreads();

    const int l = tid & 63;
    const int off = zi * 64 + l;
    if (off < ZBP) {
        for (int k = 0; k < 16; ++k) {
            int tr = r0 * 16 + k;
            imgT[(size_t)(t0 + tr) * ZBP + off] = lds[l * 65 + tr];  // coalesced along z
        }
    }
}

// ---------------------------------------------------------------------------
// Phase B: sequential sign-LMS scan — producer/consumer, MINIMAL-ISSUE consumer.
//
// Round-9 post-mortem (decisive): shortening the dep chain to ~4 ops made it
// 45% SLOWER, with total VALU-cycles up proportionally to instruction count.
// => the consumer is ISSUE-bound at ~6 cyc/instruction for a lone wave
// (r3: 19 instr -> 143 cyc; r6: 21 -> 127; r9: 34 -> 185).  The only lever
// is instructions/step.  This round: round-6 verified shell (7 DMA producer
// waves -- NOT reg+ds_write, which steals DS-pipe slots, r7) with the step
// stripped to ~16 issue slots:
//   - race-fixed RTISSUE (r9): asm ds_read2 writes the long-lived arrays
//     DIRECTLY ("=&v"), no movs between issue and lgkmcnt wait (r8 bug).
//   - original 13-op recurrence (no candidates).
//   - UNCONDITIONAL stores: dead lanes (feeders 0-2, band>=ZB) store junk to
//     a dump column in out[5N,6N) (every cell later overwritten by finalize's
//     reconstructed write); removes per-step exec-mask churn.  Dump address
//     5N+70+lane+t*ZB stays < 6N for all t<YX.
//
// Data path bit-exact vs all passing rounds: {nx,ny,nz,s} = LDS dwords at row
// positions {lane-3..lane}; d = 3-mul + left-to-right 2-add; sign(s-clip(d))
// == sign(s-d) since |s| < 32767; w' = fma(+-MU,n,w); stores UNCLIPPED d
// (finalize clamps).  NaN-safe: if d is junk-NaN (dead lanes reading PAD),
// both compares are false -> sg=0 -> w stays finite.
// ---------------------------------------------------------------------------
__global__ __launch_bounds__(512, 1) void scan_kernel(const float* __restrict__ imgT,
                                                      const float* __restrict__ w0g,
                                                      float* __restrict__ dT) {
    __shared__ float ldsf[PAD + 2 * SS * 64];  // 64.02 KB

    const int tid = threadIdx.x;
    const int lane = tid & 63;
    const int wv = tid >> 6;                  // 0 = consumer, 1..7 = producers
    const int b = blockIdx.x;                 // 0..3
    const int goff = 61 * b + lane;           // imgT row offset this lane loads
    const float* gsrc = imgT + goff;

    // consumer-only state (harmless on producers)
    const int band = 61 * b + lane - 3;
    const bool live = (lane >= 3) && (band < ZB);
    const int wband = band < 0 ? 0 : (band > ZB - 1 ? ZB - 1 : band);
    float w0 = w0g[wband * 3 + 0];
    float w1 = w0g[wband * 3 + 1];
    float w2 = w0g[wband * 3 + 2];
    // live -> real dT column; dead -> dump column inside out[5N,6N)
    float* const sbase = live ? (dT + band) : (dT + NTOT + 70 + lane);

    // producer: stage superstep st into buffer st&1 (rows strided by 7 waves)
    auto stage = [&](int st) {
        float* lp = ldsf + PAD + (st & 1) * (SS * 64);
        const float* gp = gsrc + (size_t)st * (SS * ZBP);
        for (int r = wv - 1; r < SS; r += 7)
            GL_LDS4(gp + (size_t)r * ZBP, lp + r * 64);
    };

    // sub-tile register buffers: Xa[k] = {nx(lane-3), ny(lane-2)},
    //                            Xb[k] = {nz(lane-1), s(lane)}
    v2f Aa[16], Ab[16], Ba[16], Bb[16];

    // batch-ISSUE one 16-step sub-tile; asm writes the ARRAYS directly (no
    // intermediate copies -> nothing reads the regs before KWAIT).
#define RTISSUE(XA, XB, bsel, st_)                                             \
    {                                                                          \
        uint32_t a0_ = (uint32_t)(size_t)(__attribute__((address_space(3)))    \
            float*)(ldsf + (PAD + (bsel) * (SS * 64) + (st_) * (16 * 64)       \
                            + lane - 3));                                      \
        _Pragma("unroll") for (int k = 0; k < 16; ++k) {                       \
            uint32_t a_ = a0_ + (uint32_t)(k * 256);                           \
            asm volatile("ds_read2_b32 %0, %2 offset0:0 offset1:1\n\t"         \
                         "ds_read2_b32 %1, %2 offset0:2 offset1:3"             \
                         : "=&v"(XA[k]), "=&v"(XB[k])                          \
                         : "v"(a_));                                           \
        }                                                                      \
    }

#define KWAIT()                                                                \
    {                                                                          \
        asm volatile("s_waitcnt lgkmcnt(0)" ::: "memory");                     \
        __builtin_amdgcn_sched_barrier(0);                                     \
    }

#define CP(BA, BB, st_)                                                        \
    {                                                                          \
        float* op = sbase + ((size_t)ss * SS + (st_) * 16) * ZB;               \
        _Pragma("unroll") for (int i = 0; i < 16; ++i) {                       \
            const float nx = BA[i].x, ny = BA[i].y;                            \
            const float nz = BB[i].x, s_ = BB[i].y;                            \
            float d = __fadd_rn(                                               \
                __fadd_rn(__fmul_rn(w0, nz), __fmul_rn(w1, ny)),               \
                __fmul_rn(w2, nx));                                            \
            float sg = (s_ > d) ? kMU() : ((s_ < d) ? -kMU() : 0.0f);          \
            w0 = __builtin_fmaf(sg, nz, w0);                                   \
            w1 = __builtin_fmaf(sg, ny, w1);                                   \
            w2 = __builtin_fmaf(sg, nx, w2);                                   \
            op[(size_t)i * ZB] = d;                                            \
        }                                                                      \
    }

    if (wv != 0) stage(0);
    __syncthreads();

    for (int ss = 0; ss < NSS; ++ss) {
        if (wv != 0) {
            if (ss + 1 < NSS) stage(ss + 1);
        } else {
            const int csel = ss & 1;
            // 8 sub-tiles of 16 steps; batch-issue one sub-tile ahead
            RTISSUE(Aa, Ab, csel, 0); KWAIT();
            RTISSUE(Ba, Bb, csel, 1); CP(Aa, Ab, 0); KWAIT();
            RTISSUE(Aa, Ab, csel, 2); CP(Ba, Bb, 1); KWAIT();
            RTISSUE(Ba, Bb, csel, 3); CP(Aa, Ab, 2); KWAIT();
            RTISSUE(Aa, Ab, csel, 4); CP(Ba, Bb, 3); KWAIT();
            RTISSUE(Ba, Bb, csel, 5); CP(Aa, Ab, 4); KWAIT();
            RTISSUE(Aa, Ab, csel, 6); CP(Ba, Bb, 5); KWAIT();
            RTISSUE(Ba, Bb, csel, 7); CP(Aa, Ab, 6); KWAIT();
            CP(Ba, Bb, 7);
        }
        __syncthreads();  // producers drained; buffer handoff
    }

#undef RTISSUE
#undef KWAIT
#undef CP
}

// ---------------------------------------------------------------------------
// Phase C: elementwise outputs from dT + image. (unchanged, verified)
// ---------------------------------------------------------------------------
__global__ __launch_bounds__(256) void finalize_kernel(const float* __restrict__ img,
                                                       const float* __restrict__ dT,
                                                       float* __restrict__ out) {
    __shared__ float lds[64 * ZB];  // 51.7 KB
    const int t0 = blockIdx.x * 64;
    const float* src = dT + (size_t)t0 * ZB;
    for (int i = threadIdx.x; i < 64 * ZB; i += 256) lds[i] = src[i];
    __syncthreads();

    for (int k = 0; k < 51; ++k) {
        int e = k * 256 + threadIdx.x;
        if (e < 64 * ZB) {
            int zz = e >> 6;
            int tl = e & 63;
            float dv = lds[tl * ZB + zz];            // stride 202 -> 2-way bank alias (free)
            float pred = fminf(fmaxf(dv, MINV), MAXV);
            size_t o = (size_t)zz * YX + t0 + tl;
            float s = img[o];
            float res = __fsub_rn(s, pred);
            int q = (int)rintf(res);                  // round-half-even == jnp.round
            int m = (q >= 0) ? (2 * q) : (-2 * q - 1);
            out[o] = pred;                            // predictions
            out[NTOT + o] = res;                      // residuals
            out[2 * NTOT + o] = res;                  // quantized_residuals
            out[3 * NTOT + o] = (float)m;             // mapped_indices
            out[5 * NTOT + o] = __fadd_rn(pred, res); // reconstructed (overwrites scan dump junk)
        }
    }
}

// ---------------------------------------------------------------------------
// Phase D: sample_representatives = image. (unchanged)
// ---------------------------------------------------------------------------
__global__ __launch_bounds__(256) void repr_kernel(const float4* __restrict__ img4,
                                                   float4* __restrict__ out4) {
    size_t n4 = NTOT / 4;
    for (size_t i = (size_t)blockIdx.x * blockDim.x + threadIdx.x; i < n4;
         i += (size_t)gridDim.x * blockDim.x)
        out4[i] = img4[i];
}

extern "C" void kernel_launch(void* const* d_in, const int* in_sizes, int n_in,
                              void* d_out, int out_size, void* d_ws, size_t ws_size,
                              hipStream_t stream) {
    const float* img = (const float*)d_in[0];
    const float* w0g = (const float*)d_in[1];
    float* out = (float*)d_out;

    // Scratch carved out of d_out (dead before the final writers touch it):
    //   imgT = out[0 .. YX*ZBP+64) floats (54.5 MB; +64 slack keeps block-3
    //          tail-lane junk reads in-bounds)
    //   dT   = out[4N .. 5N) floats (later overwritten by repr_kernel)
    //   scan dead-lane dump = out[5N+70 .. 6N) column walk (overwritten by
    //          finalize's reconstructed pass)
    float* imgT = out;
    float* dT = out + 4 * NTOT;

    tr_kernel<<<dim3(YX / 64, 4), 256, 0, stream>>>(img, imgT);
    scan_kernel<<<4, 512, 0, stream>>>(imgT, w0g, dT);
    finalize_kernel<<<YX / 64, 256, 0, stream>>>(img, dT, out);
    repr_kernel<<<4096, 256, 0, stream>>>((const float4*)img, (float4*)(out + 4 * NTOT));
}